// Round 7
// baseline (36.451 us; speedup 1.0000x reference)
//
#include <hip/hip_runtime.h>

#define TILE  64   // positions per tile
#define LS    67   // LDS row stride: 67%32=3 -> conflict-free A-writes, scalar C-reads
#define OUTCH 87   // 2 coord + 80 scores + 4 bbox + 1 ctr
#define NF4   1392 // TILE*OUTCH/4

typedef float f32x4 __attribute__((ext_vector_type(4)));

__global__ __launch_bounds__(256) void fcos_filter_kernel(
    const float* __restrict__ cl0, const float* __restrict__ bb0, const float* __restrict__ ct0,
    const float* __restrict__ cl1, const float* __restrict__ bb1, const float* __restrict__ ct1,
    const float* __restrict__ cl2, const float* __restrict__ bb2, const float* __restrict__ ct2,
    const float* __restrict__ cl3, const float* __restrict__ bb3, const float* __restrict__ ct3,
    const float* __restrict__ cl4, const float* __restrict__ bb4, const float* __restrict__ ct4,
    float* __restrict__ out)
{
    __shared__ float lds[85 * LS];    // 22,780 B
    __shared__ float s_flag[TILE];    // -> 7 blocks/CU by LDS

    const int P   = blockIdx.x;       // pair index; 2 consecutive tiles per block
    const int tid = threadIdx.x;

    // ---- level decode; both tiles' (img, tile-in-img) via per-branch const divs ----
    const float *cls, *bbx, *ctr;
    int HW, W, str, ksh, iA, tA, iB, tB;
    size_t obase;
    if (P < 1600)      { cls=cl0;bbx=bb0;ctr=ct0;HW=25600;W=160;str=8;  ksh=4;obase=0u;
        const int a=2*P;        iA=a/400; tA=a-iA*400; const int b=a+1; iB=b/400; tB=b-iB*400; }
    else if (P < 2000) { cls=cl1;bbx=bb1;ctr=ct1;HW=6400; W=80; str=16; ksh=3;obase=17817600u;
        const int a=2*(P-1600); iA=a/100; tA=a-iA*100; const int b=a+1; iB=b/100; tB=b-iB*100; }
    else if (P < 2100) { cls=cl2;bbx=bb2;ctr=ct2;HW=1600; W=40; str=32; ksh=2;obase=22272000u;
        const int a=2*(P-2000); iA=a/25;  tA=a-iA*25;  const int b=a+1; iB=b/25;  tB=b-iB*25;  }
    else if (P < 2128) { cls=cl3;bbx=bb3;ctr=ct3;HW=400;  W=20; str=64; ksh=1;obase=23385600u;
        const int a=2*(P-2100); iA=a/7;   tA=a-iA*7;   const int b=a+1; iB=b/7;   tB=b-iB*7;   }
    else               { cls=cl4;bbx=bb4;ctr=ct4;HW=100;  W=10; str=128;ksh=0;obase=23664000u;
        const int a=2*(P-2128); iA=a>>1;  tA=a&1;      const int b=a+1; iB=b>>1;  tB=b&1;      }

    const int pA = tA * TILE, pB = tB * TILE;
    const int vA = min(TILE, HW - pA), vB = min(TILE, HW - pB);

    const int  lane_c = tid >> 4;          // 0..15 channel group
    const int  q4     = (tid & 15) << 2;   // position base 0,4,...,60
    const bool okA    = q4 < vA, okB = q4 < vB;

    auto load_tile = [&](float4 v[6], int img_, int p0_, bool ok_) {
        if (ok_) {
            const float* ab = cls + ((size_t)img_ * 80 + lane_c) * HW + p0_ + q4;
            v[0] = *reinterpret_cast<const float4*>(ab);
            v[1] = *reinterpret_cast<const float4*>(ab + (size_t)16 * HW);
            v[2] = *reinterpret_cast<const float4*>(ab + (size_t)32 * HW);
            v[3] = *reinterpret_cast<const float4*>(ab + (size_t)48 * HW);
            v[4] = *reinterpret_cast<const float4*>(ab + (size_t)64 * HW);
            if (tid < 80) {
                const float* s5 = (lane_c < 4)
                    ? bbx + ((size_t)img_ * 4 + lane_c) * HW + p0_ + q4
                    : ctr + (size_t)img_ * HW + p0_ + q4;
                v[5] = *reinterpret_cast<const float4*>(s5);
            }
        }
    };

    auto commit_tile = [&](const float4 v[6], bool ok_) {
        float4 fm; fm.x = fm.y = fm.z = fm.w = -1e30f;
        if (ok_) {
            #pragma unroll
            for (int k = 0; k < 5; ++k) {
                const int a_ = (16 * k + lane_c) * LS + q4;
                lds[a_ + 0] = v[k].x; lds[a_ + 1] = v[k].y;
                lds[a_ + 2] = v[k].z; lds[a_ + 3] = v[k].w;
                fm.x = fmaxf(fm.x, v[k].x);
                fm.y = fmaxf(fm.y, v[k].y);
                fm.z = fmaxf(fm.z, v[k].z);
                fm.w = fmaxf(fm.w, v[k].w);
            }
            if (tid < 80) {
                const int a_ = (80 + lane_c) * LS + q4;
                lds[a_ + 0] = v[5].x; lds[a_ + 1] = v[5].y;
                lds[a_ + 2] = v[5].z; lds[a_ + 3] = v[5].w;
            }
        }
        fm.x = fmaxf(fm.x, __shfl_xor(fm.x, 16));
        fm.y = fmaxf(fm.y, __shfl_xor(fm.y, 16));
        fm.z = fmaxf(fm.z, __shfl_xor(fm.z, 16));
        fm.w = fmaxf(fm.w, __shfl_xor(fm.w, 16));
        fm.x = fmaxf(fm.x, __shfl_xor(fm.x, 32));
        fm.y = fmaxf(fm.y, __shfl_xor(fm.y, 32));
        fm.z = fmaxf(fm.z, __shfl_xor(fm.z, 32));
        fm.w = fmaxf(fm.w, __shfl_xor(fm.w, 32));
        if (tid < TILE) s_flag[tid] = 0.0f;
        __syncthreads();
        if ((tid & 63) < 16) {
            if (fm.x > 0.5f) s_flag[q4 + 0] = 1.0f;
            if (fm.y > 0.5f) s_flag[q4 + 1] = 1.0f;
            if (fm.z > 0.5f) s_flag[q4 + 2] = 1.0f;
            if (fm.w > 0.5f) s_flag[q4 + 3] = 1.0f;
        }
        __syncthreads();
    };

    auto store_tile = [&](int img_, int p0_, int valid_) {
        float* dst = out + obase + ((size_t)img_ * HW + p0_) * OUTCH;
        const int nmax = valid_ * OUTCH;
        #pragma unroll
        for (int r = 0; r < 6; ++r) {
            const int f4 = tid + 256 * r;
            if (r == 5 && f4 >= NF4) break;
            const int e0 = f4 * 4;
            if (e0 >= nmax) break;
            const int p  = e0 / OUTCH;          // magic-mul div by 87
            const int ch = e0 - p * OUTCH;
            float vals[4];
            #pragma unroll
            for (int j = 0; j < 4; ++j) {
                int chj = ch + j, pj = p;
                if (chj >= OUTCH) { chj -= OUTCH; pj += 1; }
                const float m = s_flag[pj];
                float val;
                if (chj >= 2) {
                    val = lds[(chj - 2) * LS + pj] * m;
                } else {
                    const int pg = p0_ + pj;
                    const int tt = pg >> ksh;   // = pg / (W/10)
                    const int y  = tt / 10;     // magic-mul div by 10
                    const int x  = pg - y * W;
                    val = (float)(((chj == 0) ? x : y) * str + (str >> 1)) * m;
                }
                vals[j] = val;
            }
            if (e0 + 4 <= nmax) {
                f32x4 o; o.x = vals[0]; o.y = vals[1]; o.z = vals[2]; o.w = vals[3];
                *reinterpret_cast<f32x4*>(dst + e0) = o;
            } else {                            // ragged tail (level 3/4 edge blocks)
                #pragma unroll
                for (int j = 0; j < 4; ++j)
                    if (e0 + j < nmax) dst[e0 + j] = vals[j];
            }
        }
    };

    // ---- pipelined 2-tile schedule (T14: issue B early, land after store A) ----
    float4 va[6], vb[6];
    load_tile(va, iA, pA, okA);          // tile A loads
    commit_tile(va, okA);                // LDS + flags for A (frees A regs)
    load_tile(vb, iB, pB, okB);          // issue B: in flight across store of A
    store_tile(iA, pA, vA);              // store A (B latency hides here)
    __syncthreads();                     // LDS reads of A done before overwrite
    commit_tile(vb, okB);                // waits vmcnt for B regs
    store_tile(iB, pB, vB);
}

extern "C" void kernel_launch(void* const* d_in, const int* in_sizes, int n_in,
                              void* d_out, int out_size, void* d_ws, size_t ws_size,
                              hipStream_t stream) {
    (void)in_sizes; (void)n_in; (void)out_size; (void)d_ws; (void)ws_size;
    fcos_filter_kernel<<<2136, 256, 0, stream>>>(
        (const float*)d_in[0],  (const float*)d_in[1],  (const float*)d_in[2],
        (const float*)d_in[3],  (const float*)d_in[4],  (const float*)d_in[5],
        (const float*)d_in[6],  (const float*)d_in[7],  (const float*)d_in[8],
        (const float*)d_in[9],  (const float*)d_in[10], (const float*)d_in[11],
        (const float*)d_in[12], (const float*)d_in[13], (const float*)d_in[14],
        (float*)d_out);
}